// Round 7
// baseline (457.045 us; speedup 1.0000x reference)
//
#include <hip/hip_runtime.h>

#define N_IMG 9216
#define DFEAT 1024
#define NBR 72           // 128-row panels
#define NPAIR 1332       // sum over bcol<36 of min(72, 2*bcol+2)

typedef __attribute__((ext_vector_type(8))) short short8;
typedef __attribute__((ext_vector_type(4))) float floatx4;
typedef __attribute__((ext_vector_type(16))) float floatx16;
typedef __attribute__((ext_vector_type(4))) int intx4;
typedef __attribute__((ext_vector_type(8))) int intx8;

// exp2-folded constants: sim = exp2(delta - gamma * rcp(1+u))
//   delta_ij = Pi*Pj          (P = sqrt(s) * C2, C2 = sqrt(2*log2e/1024))
//   gamma_ij = s~i + s~j + delta_ij   (s~ = s * C1, C1 = log2e/1024)
#define C1F 0.0014088818759657845f
#define C2F 0.05308355472172724f

__device__ __forceinline__ void async_copy16(const void* g, void* l) {
  __builtin_amdgcn_global_load_lds((const __attribute__((address_space(1))) void*)g,
                                   (__attribute__((address_space(3))) void*)l,
                                   16, 0, 0);
}

__device__ __forceinline__ unsigned short f2bf(float x) {
  union { float f; unsigned u; } a; a.f = x;
  unsigned u = a.u;
  u += 0x7fffu + ((u >> 16) & 1u);   // round-to-nearest-even
  return (unsigned short)(u >> 16);
}

// ---- conflict-free LDS swizzle (64 B rows, 2 rows per 128-B line) ----
// line L = r>>1; slot of (row parity rp, chunk c) = 2*((c+L)&3) | rp.
// any 8 consecutive fragment-read lanes cover all 8 granule slots.
__device__ __forceinline__ size_t sw_src(int P) {   // phys chunk -> src offset
  int L = P >> 3, s = P & 7;
  int row = 2 * L + (s & 1);
  int c = ((s >> 1) - L) & 3;
  return (size_t)row * DFEAT + (size_t)c * 16;
}
__device__ __forceinline__ intx4 ld16s(const unsigned char* base, int r, int c) {
  int L = r >> 1;
  int slot = (((c + L) & 3) << 1) | (r & 1);
  return *(const intx4*)(base + L * 128 + slot * 16);
}
__device__ __forceinline__ intx8 ldfrags(const unsigned char* base, int r, int kh) {
  intx4 lo = ld16s(base, r, kh * 2);
  intx4 hi = ld16s(base, r, kh * 2 + 1);
  intx8 v;
  v[0] = lo[0]; v[1] = lo[1]; v[2] = lo[2]; v[3] = lo[3];
  v[4] = hi[0]; v[5] = hi[1]; v[6] = hi[2]; v[7] = hi[3];
  return v;
}

// ---- kernel 1: fp32 -> NORMALIZED fp8(e4m3) rows + s~/P; also W1^T bf16; init sums ----
__global__ __launch_bounds__(256) void convert_prep(const float* __restrict__ f,
                                                    const float* __restrict__ W1,
                                                    unsigned char* __restrict__ fb8,
                                                    float* __restrict__ sL,
                                                    float* __restrict__ pL,
                                                    unsigned short* __restrict__ W1t,
                                                    double* __restrict__ sums) {
  int b = blockIdx.x, t = threadIdx.x;
  if (b < 2304) {
    int lane = t & 63, wave = t >> 6;
    int row = b * 4 + wave;                      // one wave per row
    const float4* src = (const float4*)f + (size_t)row * 256;
    unsigned int* dst = (unsigned int*)(fb8 + (size_t)row * DFEAT);
    float4 v0 = src[lane], v1 = src[64 + lane], v2 = src[128 + lane], v3 = src[192 + lane];
    float s = v0.x * v0.x + v0.y * v0.y + v0.z * v0.z + v0.w * v0.w
            + v1.x * v1.x + v1.y * v1.y + v1.z * v1.z + v1.w * v1.w
            + v2.x * v2.x + v2.y * v2.y + v2.z * v2.z + v2.w * v2.w
            + v3.x * v3.x + v3.y * v3.y + v3.z * v3.z + v3.w * v3.w;
#pragma unroll
    for (int off = 32; off > 0; off >>= 1) s += __shfl_xor(s, off, 64);
    float rinv = rsqrtf(s);
    float4 vv[4] = {v0, v1, v2, v3};
#pragma unroll
    for (int j = 0; j < 4; j++) {
      float4 v = vv[j];
      int pk = __builtin_amdgcn_cvt_pk_fp8_f32(v.x * rinv, v.y * rinv, 0, false);
      pk = __builtin_amdgcn_cvt_pk_fp8_f32(v.z * rinv, v.w * rinv, pk, true);
      dst[j * 64 + lane] = (unsigned int)pk;
    }
    if (lane == 0) {
      sL[row] = s * C1F;
      pL[row] = sqrtf(s) * C2F;
    }
  } else {
    int j = b - 2304;                            // W1 column j -> W1t row j
    if (j == 0 && t < 2) sums[t] = 0.0;
    for (int k = t; k < DFEAT; k += 256)
      W1t[(size_t)j * DFEAT + k] = f2bf(W1[(size_t)k * 128 + j]);
  }
}

// ---- kernel 2: Gram via MX-fp8 MFMA, 128x256 tiles, LDS double-buffered ----
__global__ __launch_bounds__(256, 2) void gram_sim(const unsigned char* __restrict__ fb8,
                                                   const float* __restrict__ sL,
                                                   const float* __restrict__ pL,
                                                   double* __restrict__ sums) {
  // decode blockIdx -> (bcol, brow), brow < min(72, 2*bcol+2)
  int rem = blockIdx.x, bcol = 0;
  for (;;) {
    int mlim = 2 * bcol + 2; if (mlim > NBR) mlim = NBR;
    if (rem < mlim) break;
    rem -= mlim; bcol++;
  }
  int brow = rem;

  __shared__ __align__(16) unsigned char Ab[2][8192];   // 128 rows x 64 B, swizzled
  __shared__ __align__(16) unsigned char Bb[2][16384];  // 256 rows x 64 B, swizzled
  __shared__ float sA[128], pA[128], sB[256], pB[256];
  __shared__ float wpart[4];

  int t = threadIdx.x, lane = t & 63, wave = t >> 6;
  if (t < 128) { sA[t] = sL[brow * 128 + t]; pA[t] = pL[brow * 128 + t]; }
  sB[t] = sL[bcol * 256 + t];
  pB[t] = pL[bcol * 256 + t];

  const unsigned char* Asrc = fb8 + (size_t)brow * 128 * DFEAT;
  const unsigned char* Bsrc = fb8 + (size_t)bcol * 256 * DFEAT;

  const size_t d0 = sw_src(t);
  const size_t d1 = sw_src(t + 256);
  const size_t d2 = sw_src(t + 512);
  const size_t d3 = sw_src(t + 768);

  floatx16 acc[2][4];
#pragma unroll
  for (int mi = 0; mi < 2; mi++)
#pragma unroll
    for (int ni = 0; ni < 4; ni++)
#pragma unroll
      for (int e = 0; e < 16; e++) acc[mi][ni][e] = 0.f;

  const int wr = (wave & 1) * 64, wc = (wave >> 1) * 128;
  const int r32 = lane & 31, kh = lane >> 5;

  // prologue: stage kb=0 into buffer 0
  async_copy16(Asrc + d0, &Ab[0][t * 16]);
  async_copy16(Asrc + d1, &Ab[0][(t + 256) * 16]);
  async_copy16(Bsrc + d0, &Bb[0][t * 16]);
  async_copy16(Bsrc + d1, &Bb[0][(t + 256) * 16]);
  async_copy16(Bsrc + d2, &Bb[0][(t + 512) * 16]);
  async_copy16(Bsrc + d3, &Bb[0][(t + 768) * 16]);

  for (int kb = 0; kb < 16; kb++) {
    __syncthreads();
    if (kb < 15) {
      const int nb = (kb + 1) & 1;
      const size_t k0 = (size_t)(kb + 1) * 64;
      async_copy16(Asrc + d0 + k0, &Ab[nb][t * 16]);
      async_copy16(Asrc + d1 + k0, &Ab[nb][(t + 256) * 16]);
      async_copy16(Bsrc + d0 + k0, &Bb[nb][t * 16]);
      async_copy16(Bsrc + d1 + k0, &Bb[nb][(t + 256) * 16]);
      async_copy16(Bsrc + d2 + k0, &Bb[nb][(t + 512) * 16]);
      async_copy16(Bsrc + d3 + k0, &Bb[nb][(t + 768) * 16]);
    }
    const unsigned char* Ac = Ab[kb & 1];
    const unsigned char* Bc = Bb[kb & 1];
    intx8 a[2], b[4];
#pragma unroll
    for (int mi = 0; mi < 2; mi++) a[mi] = ldfrags(Ac, wr + mi * 32 + r32, kh);
#pragma unroll
    for (int ni = 0; ni < 4; ni++) b[ni] = ldfrags(Bc, wc + ni * 32 + r32, kh);
#pragma unroll
    for (int mi = 0; mi < 2; mi++)
#pragma unroll
      for (int ni = 0; ni < 4; ni++)
        acc[mi][ni] = __builtin_amdgcn_mfma_scale_f32_32x32x64_f8f6f4(
            a[mi], b[ni], acc[mi][ni], 0, 0, 0, 0x7F7F7F7F, 0, 0x7F7F7F7F);
  }

  // epilogue: u = cos. C/D layout col=lane&31, row=(reg&3)+8*(reg>>2)+4*kh
  // loop order keeps live set small: si/pi are 2 scalars reloaded per (mi,reg).
  const bool interior = (brow < 2 * bcol);
  float sjv[4], pjv[4];
#pragma unroll
  for (int ni = 0; ni < 4; ni++) {
    int j_loc = wc + ni * 32 + r32;
    sjv[ni] = sB[j_loc];
    pjv[ni] = pB[j_loc];
  }
  float lsum = 0.f;
#pragma unroll
  for (int mi = 0; mi < 2; mi++) {
    const int rbase = wr + mi * 32 + 4 * kh;
#pragma unroll
    for (int reg = 0; reg < 16; reg++) {
      const int i_loc = rbase + (reg & 3) + 8 * (reg >> 2);
      const float si = sA[i_loc], pi = pA[i_loc];
      if (interior) {
#pragma unroll
        for (int ni = 0; ni < 4; ni++) {
          float u = acc[mi][ni][reg];
          float r = __builtin_amdgcn_rcpf(1.f + u);
          float del = pi * pjv[ni];
          float gam = si + sjv[ni] + del;
          lsum += __builtin_amdgcn_exp2f(fmaf(-gam, r, del));
        }
      } else {
        int i_g = brow * 128 + i_loc;
#pragma unroll
        for (int ni = 0; ni < 4; ni++) {
          int j_g = bcol * 256 + wc + ni * 32 + r32;
          float u = acc[mi][ni][reg];
          float r = __builtin_amdgcn_rcpf(1.f + u);
          float del = pi * pjv[ni];
          float gam = si + sjv[ni] + del;
          float sim = __builtin_amdgcn_exp2f(fmaf(-gam, r, del));
          lsum += (i_g < j_g) ? 2.f * sim : (i_g == j_g ? 1.f : 0.f);
        }
      }
    }
  }
  if (interior) lsum *= 2.f;
#pragma unroll
  for (int off = 32; off > 0; off >>= 1) lsum += __shfl_down(lsum, off, 64);
  if (lane == 0) wpart[wave] = lsum;
  __syncthreads();
  if (t == 0)
    atomicAdd(&sums[0], (double)(wpart[0] + wpart[1] + wpart[2] + wpart[3]));
}

// ---- kernel 3: full MLP, 32 rows/block (288 blocks): L1 bf16 MFMA, L2/L3 fp32 in LDS ----
__global__ __launch_bounds__(256) void mlp_full(const float* __restrict__ f,
                                                const unsigned short* __restrict__ W1t,
                                                const float* __restrict__ scores,
                                                const float* __restrict__ W1,
                                                const float* __restrict__ b1,
                                                const float* __restrict__ g1,
                                                const float* __restrict__ be1,
                                                const float* __restrict__ W2, const float* __restrict__ b2,
                                                const float* __restrict__ g2, const float* __restrict__ be2,
                                                const float* __restrict__ W3, const float* __restrict__ b3,
                                                double* __restrict__ sums) {
  int r0 = blockIdx.x * 32;

  __shared__ __align__(16) float As32[32 * 32];         // 4 KB, XOR-swizzled chunks
  __shared__ __align__(16) unsigned short Bs[128 * 32]; // 8 KB, XOR-swizzled chunks
  __shared__ float h1s[32][128];                        // 16 KB
  __shared__ float h2s[32][65];                         // 8.3 KB
  __shared__ float sc[32], b1s[128], g1s[128], be1s[128], wls[128], ls[32];

  int t = threadIdx.x, lane = t & 63, wave = t >> 6;
  if (t < 32) sc[t] = scores[r0 + t];
  if (t < 128) {
    b1s[t] = b1[t]; g1s[t] = g1[t]; be1s[t] = be1[t];
    wls[t] = W1[(size_t)DFEAT * 128 + t];
  }

  floatx4 acc[4];
#pragma unroll
  for (int b = 0; b < 4; b++) acc[b] = (floatx4){0.f, 0.f, 0.f, 0.f};

  const int wr = (wave & 1) * 16, wc = (wave >> 1) * 64;

  for (int k0 = 0; k0 < DFEAT; k0 += 32) {
    __syncthreads();
    {
      // A: 256 chunks (32 rows x 8/row, 1 row per 128-B line); phys p holds p^(r&7)
      int rA = t >> 3, p = t & 7, l = p ^ (rA & 7);
      async_copy16(f + (size_t)(r0 + rA) * DFEAT + k0 + l * 4, (char*)As32 + t * 16);
      // B: 512 chunks (128 rows x 4); phys p holds logical p^(r&3)
      int c = t, rB = c >> 2; p = c & 3; l = p ^ (rB & 3);
      async_copy16(W1t + (size_t)rB * DFEAT + k0 + l * 8, (char*)Bs + c * 16);
      c = t + 256; rB = c >> 2; p = c & 3; l = p ^ (rB & 3);
      async_copy16(W1t + (size_t)rB * DFEAT + k0 + l * 8, (char*)Bs + c * 16);
    }
    __syncthreads();

    const int mrow = lane & 15, kq = (lane >> 4) * 8;
    short8 a, b[4];
    {
      int row = wr + mrow;
      int l0 = kq >> 2;
      int p0 = l0 ^ (row & 7), p1 = (l0 + 1) ^ (row & 7);
      float4 f0 = *(const float4*)&As32[row * 32 + p0 * 4];
      float4 f1 = *(const float4*)&As32[row * 32 + p1 * 4];
      a[0] = (short)f2bf(f0.x); a[1] = (short)f2bf(f0.y);
      a[2] = (short)f2bf(f0.z); a[3] = (short)f2bf(f0.w);
      a[4] = (short)f2bf(f1.x); a[5] = (short)f2bf(f1.y);
      a[6] = (short)f2bf(f1.z); a[7] = (short)f2bf(f1.w);
    }
#pragma unroll
    for (int nt = 0; nt < 4; nt++) {
      int row = wc + nt * 16 + mrow;
      int p = (kq >> 3) ^ (row & 3);
      b[nt] = *(const short8*)&Bs[row * 32 + p * 8];
    }
#pragma unroll
    for (int nt = 0; nt < 4; nt++)
      acc[nt] = __builtin_amdgcn_mfma_f32_16x16x32_bf16(a, b[nt], acc[nt], 0, 0, 0);
  }

  const float inv = 1.0f / sqrtf(1.0f + 1e-5f);
  const int rq = (lane >> 4) * 4, cn = lane & 15;
#pragma unroll
  for (int nt = 0; nt < 4; nt++) {
    int j = wc + nt * 16 + cn;
    float bj = b1s[j], gj = g1s[j] * inv, bej = be1s[j], wj = wls[j];
#pragma unroll
    for (int rr = 0; rr < 4; rr++) {
      int iL = wr + rq + rr;
      float pre = acc[nt][rr] + sc[iL] * wj + bj;
      h1s[iL][j] = fmaxf(gj * pre + bej, 0.f);
    }
  }
  __syncthreads();

  // layer 2: 128 -> 64. j = t&63, 8 rows/thread (broadcast LDS reads)
  {
    int j = t & 63, rg = (t >> 6) * 8;
    float a2[8];
#pragma unroll
    for (int rr = 0; rr < 8; rr++) a2[rr] = 0.f;
    for (int k = 0; k < 128; k++) {
      float w = W2[k * 64 + j];
#pragma unroll
      for (int rr = 0; rr < 8; rr++) a2[rr] = fmaf(h1s[rg + rr][k], w, a2[rr]);
    }
    float scv = g2[j] * inv, bi = b2[j], be = be2[j];
#pragma unroll
    for (int rr = 0; rr < 8; rr++)
      h2s[rg + rr][j] = fmaxf(scv * (a2[rr] + bi) + be, 0.f);
  }
  __syncthreads();

  // layer 3: 64 -> 1 + sigmoid
  if (t < 32) {
    float z = b3[0];
#pragma unroll
    for (int k = 0; k < 64; k++) z = fmaf(h2s[t][k], W3[k], z);
    ls[t] = 1.f / (1.f + __expf(-z));
  }
  __syncthreads();
  if (t == 0) {
    float s = 0.f;
#pragma unroll
    for (int iL = 0; iL < 32; iL++) s += ls[iL];
    atomicAdd(&sums[1], (double)s);
  }
}

// ---- kernel 4: combine ----
__global__ void finalize(const double* __restrict__ sums, float* __restrict__ out) {
  double simmean = sums[0] / ((double)N_IMG * (double)N_IMG);
  double aggmean = sums[1] / (double)N_IMG;
  out[0] = (float)(aggmean * simmean);
}

extern "C" void kernel_launch(void* const* d_in, const int* in_sizes, int n_in,
                              void* d_out, int out_size, void* d_ws, size_t ws_size,
                              hipStream_t stream) {
  const float* f      = (const float*)d_in[0];
  const float* scores = (const float*)d_in[1];
  const float* W1 = (const float*)d_in[2];
  const float* b1 = (const float*)d_in[3];
  const float* g1 = (const float*)d_in[4];
  const float* be1 = (const float*)d_in[5];
  const float* W2 = (const float*)d_in[6];
  const float* b2 = (const float*)d_in[7];
  const float* g2 = (const float*)d_in[8];
  const float* be2 = (const float*)d_in[9];
  const float* W3 = (const float*)d_in[10];
  const float* b3 = (const float*)d_in[11];

  // workspace layout (9.77 MB total)
  char* ws = (char*)d_ws;
  unsigned char* fb8  = (unsigned char*)ws;                  // 9,437,184 B (normalized fp8)
  float* sL           = (float*)(ws + 9437184);              // 36,864 B  (s * C1)
  float* pL           = (float*)(ws + 9474048);              // 36,864 B  (sqrt(s) * C2)
  unsigned short* W1t = (unsigned short*)(ws + 9510912);     // 262,144 B
  double* sums        = (double*)(ws + 9773056);             // 16 B

  convert_prep<<<2432, 256, 0, stream>>>(f, W1, fb8, sL, pL, W1t, sums);
  gram_sim<<<NPAIR, 256, 0, stream>>>(fb8, sL, pL, sums);
  mlp_full<<<288, 256, 0, stream>>>(f, W1t, scores, W1, b1, g1, be1,
                                    W2, b2, g2, be2, W3, b3, sums);
  finalize<<<1, 1, 0, stream>>>(sums, (float*)d_out);
}

// Round 8
// 198.307 us; speedup vs baseline: 2.3047x; 2.3047x over previous
//
#include <hip/hip_runtime.h>

#define N_IMG 9216
#define DFEAT 1024
#define NBR 72           // 128-row panels
#define NPAIR 1332       // sum over bcol<36 of min(72, 2*bcol+2)

typedef __attribute__((ext_vector_type(8))) short short8;
typedef __attribute__((ext_vector_type(4))) float floatx4;
typedef __attribute__((ext_vector_type(16))) float floatx16;
typedef __attribute__((ext_vector_type(4))) int intx4;
typedef __attribute__((ext_vector_type(8))) int intx8;

// exp2-folded constants: sim = exp2(delta - gamma * rcp(1+u))
//   delta_ij = Pi*Pj          (P = sqrt(s) * C2, C2 = sqrt(2*log2e/1024))
//   gamma_ij = s~i + s~j + delta_ij   (s~ = s * C1, C1 = log2e/1024)
#define C1F 0.0014088818759657845f
#define C2F 0.05308355472172724f

__device__ __forceinline__ void async_copy16(const void* g, void* l) {
  __builtin_amdgcn_global_load_lds((const __attribute__((address_space(1))) void*)g,
                                   (__attribute__((address_space(3))) void*)l,
                                   16, 0, 0);
}

__device__ __forceinline__ unsigned short f2bf(float x) {
  union { float f; unsigned u; } a; a.f = x;
  unsigned u = a.u;
  u += 0x7fffu + ((u >> 16) & 1u);   // round-to-nearest-even
  return (unsigned short)(u >> 16);
}

// ---- conflict-free LDS swizzle (64 B rows, 2 rows per 128-B line) ----
// line L = r>>1; slot of (row parity rp, chunk c) = 2*((c+L)&3) | rp.
// any 8 consecutive fragment-read lanes cover all 8 granule slots.
// correctness verified R7 (absmax 0.0).
__device__ __forceinline__ size_t sw_src(int P) {   // phys chunk -> src offset
  int L = P >> 3, s = P & 7;
  int row = 2 * L + (s & 1);
  int c = ((s >> 1) - L) & 3;
  return (size_t)row * DFEAT + (size_t)c * 16;
}
__device__ __forceinline__ intx4 ld16s(const unsigned char* base, int r, int c) {
  int L = r >> 1;
  int slot = (((c + L) & 3) << 1) | (r & 1);
  return *(const intx4*)(base + L * 128 + slot * 16);
}
__device__ __forceinline__ intx8 ldfrags(const unsigned char* base, int r, int kh) {
  intx4 lo = ld16s(base, r, kh * 2);
  intx4 hi = ld16s(base, r, kh * 2 + 1);
  intx8 v;
  v[0] = lo[0]; v[1] = lo[1]; v[2] = lo[2]; v[3] = lo[3];
  v[4] = hi[0]; v[5] = hi[1]; v[6] = hi[2]; v[7] = hi[3];
  return v;
}

// ---- kernel 1: fp32 -> NORMALIZED fp8(e4m3) rows + s~/P; also W1^T bf16; init sums ----
__global__ __launch_bounds__(256) void convert_prep(const float* __restrict__ f,
                                                    const float* __restrict__ W1,
                                                    unsigned char* __restrict__ fb8,
                                                    float* __restrict__ sL,
                                                    float* __restrict__ pL,
                                                    unsigned short* __restrict__ W1t,
                                                    double* __restrict__ sums) {
  int b = blockIdx.x, t = threadIdx.x;
  if (b < 2304) {
    int lane = t & 63, wave = t >> 6;
    int row = b * 4 + wave;                      // one wave per row
    const float4* src = (const float4*)f + (size_t)row * 256;
    unsigned int* dst = (unsigned int*)(fb8 + (size_t)row * DFEAT);
    float4 v0 = src[lane], v1 = src[64 + lane], v2 = src[128 + lane], v3 = src[192 + lane];
    float s = v0.x * v0.x + v0.y * v0.y + v0.z * v0.z + v0.w * v0.w
            + v1.x * v1.x + v1.y * v1.y + v1.z * v1.z + v1.w * v1.w
            + v2.x * v2.x + v2.y * v2.y + v2.z * v2.z + v2.w * v2.w
            + v3.x * v3.x + v3.y * v3.y + v3.z * v3.z + v3.w * v3.w;
#pragma unroll
    for (int off = 32; off > 0; off >>= 1) s += __shfl_xor(s, off, 64);
    float rinv = rsqrtf(s);
    float4 vv[4] = {v0, v1, v2, v3};
#pragma unroll
    for (int j = 0; j < 4; j++) {
      float4 v = vv[j];
      int pk = __builtin_amdgcn_cvt_pk_fp8_f32(v.x * rinv, v.y * rinv, 0, false);
      pk = __builtin_amdgcn_cvt_pk_fp8_f32(v.z * rinv, v.w * rinv, pk, true);
      dst[j * 64 + lane] = (unsigned int)pk;
    }
    if (lane == 0) {
      sL[row] = s * C1F;
      pL[row] = sqrtf(s) * C2F;
    }
  } else {
    int j = b - 2304;                            // W1 column j -> W1t row j
    if (j == 0 && t < 2) sums[t] = 0.0;
    for (int k = t; k < DFEAT; k += 256)
      W1t[(size_t)j * DFEAT + k] = f2bf(W1[(size_t)k * 128 + j]);
  }
}

// ---- kernel 2: Gram via MX-fp8 MFMA, 128x256 tiles, LDS double-buffered ----
__global__ __launch_bounds__(256, 2) void gram_sim(const unsigned char* __restrict__ fb8,
                                                   const float* __restrict__ sL,
                                                   const float* __restrict__ pL,
                                                   double* __restrict__ sums) {
  // decode blockIdx -> (bcol, brow), brow < min(72, 2*bcol+2)
  int rem = blockIdx.x, bcol = 0;
  for (;;) {
    int mlim = 2 * bcol + 2; if (mlim > NBR) mlim = NBR;
    if (rem < mlim) break;
    rem -= mlim; bcol++;
  }
  int brow = rem;

  __shared__ __align__(16) unsigned char Ab[2][8192];   // 128 rows x 64 B, swizzled
  __shared__ __align__(16) unsigned char Bb[2][16384];  // 256 rows x 64 B, swizzled
  __shared__ float sA[128], pA[128], sB[256], pB[256];
  __shared__ float wpart[4];

  int t = threadIdx.x, lane = t & 63, wave = t >> 6;
  if (t < 128) { sA[t] = sL[brow * 128 + t]; pA[t] = pL[brow * 128 + t]; }
  sB[t] = sL[bcol * 256 + t];
  pB[t] = pL[bcol * 256 + t];

  const unsigned char* Asrc = fb8 + (size_t)brow * 128 * DFEAT;
  const unsigned char* Bsrc = fb8 + (size_t)bcol * 256 * DFEAT;

  const size_t d0 = sw_src(t);
  const size_t d1 = sw_src(t + 256);
  const size_t d2 = sw_src(t + 512);
  const size_t d3 = sw_src(t + 768);

  floatx16 acc[2][4];
#pragma unroll
  for (int mi = 0; mi < 2; mi++)
#pragma unroll
    for (int ni = 0; ni < 4; ni++)
#pragma unroll
      for (int e = 0; e < 16; e++) acc[mi][ni][e] = 0.f;

  const int wr = (wave & 1) * 64, wc = (wave >> 1) * 128;
  const int r32 = lane & 31, kh = lane >> 5;

  // prologue: stage kb=0 into buffer 0
  async_copy16(Asrc + d0, &Ab[0][t * 16]);
  async_copy16(Asrc + d1, &Ab[0][(t + 256) * 16]);
  async_copy16(Bsrc + d0, &Bb[0][t * 16]);
  async_copy16(Bsrc + d1, &Bb[0][(t + 256) * 16]);
  async_copy16(Bsrc + d2, &Bb[0][(t + 512) * 16]);
  async_copy16(Bsrc + d3, &Bb[0][(t + 768) * 16]);

  for (int kb = 0; kb < 16; kb++) {
    __syncthreads();
    if (kb < 15) {
      const int nb = (kb + 1) & 1;
      const size_t k0 = (size_t)(kb + 1) * 64;
      async_copy16(Asrc + d0 + k0, &Ab[nb][t * 16]);
      async_copy16(Asrc + d1 + k0, &Ab[nb][(t + 256) * 16]);
      async_copy16(Bsrc + d0 + k0, &Bb[nb][t * 16]);
      async_copy16(Bsrc + d1 + k0, &Bb[nb][(t + 256) * 16]);
      async_copy16(Bsrc + d2 + k0, &Bb[nb][(t + 512) * 16]);
      async_copy16(Bsrc + d3 + k0, &Bb[nb][(t + 768) * 16]);
    }
    const unsigned char* Ac = Ab[kb & 1];
    const unsigned char* Bc = Bb[kb & 1];
    intx8 a[2], b[4];
#pragma unroll
    for (int mi = 0; mi < 2; mi++) a[mi] = ldfrags(Ac, wr + mi * 32 + r32, kh);
#pragma unroll
    for (int ni = 0; ni < 4; ni++) b[ni] = ldfrags(Bc, wc + ni * 32 + r32, kh);
#pragma unroll
    for (int mi = 0; mi < 2; mi++)
#pragma unroll
      for (int ni = 0; ni < 4; ni++)
        acc[mi][ni] = __builtin_amdgcn_mfma_scale_f32_32x32x64_f8f6f4(
            a[mi], b[ni], acc[mi][ni], 0, 0, 0, 0x7F7F7F7F, 0, 0x7F7F7F7F);
  }

  // epilogue: R5's proven low-pressure nesting (ni -> mi -> reg), folded math.
  // C/D layout col=lane&31, row=(reg&3)+8*(reg>>2)+4*kh
  const bool interior = (brow < 2 * bcol);
  float lsum = 0.f;
#pragma unroll
  for (int ni = 0; ni < 4; ni++) {
    int j_loc = wc + ni * 32 + r32;
    float sj = sB[j_loc], pj = pB[j_loc];
    int j_g = bcol * 256 + j_loc;
#pragma unroll
    for (int mi = 0; mi < 2; mi++) {
      int rbase = wr + mi * 32 + 4 * kh;
#pragma unroll
      for (int reg = 0; reg < 16; reg++) {
        int i_loc = rbase + (reg & 3) + 8 * (reg >> 2);
        float u = acc[mi][ni][reg];
        float si = sA[i_loc], pi = pA[i_loc];
        float r = __builtin_amdgcn_rcpf(1.f + u);
        float del = pi * pj;
        float gam = si + sj + del;
        float sim = __builtin_amdgcn_exp2f(fmaf(-gam, r, del));
        if (interior) {
          lsum += sim;
        } else {
          int i_g = brow * 128 + i_loc;
          lsum += (i_g < j_g) ? 2.f * sim : (i_g == j_g ? 1.f : 0.f);
        }
      }
    }
  }
  if (interior) lsum *= 2.f;
#pragma unroll
  for (int off = 32; off > 0; off >>= 1) lsum += __shfl_down(lsum, off, 64);
  if (lane == 0) wpart[wave] = lsum;
  __syncthreads();
  if (t == 0)
    atomicAdd(&sums[0], (double)(wpart[0] + wpart[1] + wpart[2] + wpart[3]));
}

// ---- kernel 3: full MLP, 32 rows/block (288 blocks): L1 bf16 MFMA, L2/L3 fp32 in LDS ----
__global__ __launch_bounds__(256) void mlp_full(const float* __restrict__ f,
                                                const unsigned short* __restrict__ W1t,
                                                const float* __restrict__ scores,
                                                const float* __restrict__ W1,
                                                const float* __restrict__ b1,
                                                const float* __restrict__ g1,
                                                const float* __restrict__ be1,
                                                const float* __restrict__ W2, const float* __restrict__ b2,
                                                const float* __restrict__ g2, const float* __restrict__ be2,
                                                const float* __restrict__ W3, const float* __restrict__ b3,
                                                double* __restrict__ sums) {
  int r0 = blockIdx.x * 32;

  __shared__ __align__(16) float As32[32 * 32];         // 4 KB, XOR-swizzled chunks
  __shared__ __align__(16) unsigned short Bs[128 * 32]; // 8 KB, XOR-swizzled chunks
  __shared__ float h1s[32][128];                        // 16 KB
  __shared__ float h2s[32][65];                         // 8.3 KB
  __shared__ float sc[32], b1s[128], g1s[128], be1s[128], wls[128], ls[32];

  int t = threadIdx.x, lane = t & 63, wave = t >> 6;
  if (t < 32) sc[t] = scores[r0 + t];
  if (t < 128) {
    b1s[t] = b1[t]; g1s[t] = g1[t]; be1s[t] = be1[t];
    wls[t] = W1[(size_t)DFEAT * 128 + t];
  }

  floatx4 acc[4];
#pragma unroll
  for (int b = 0; b < 4; b++) acc[b] = (floatx4){0.f, 0.f, 0.f, 0.f};

  const int wr = (wave & 1) * 16, wc = (wave >> 1) * 64;

  for (int k0 = 0; k0 < DFEAT; k0 += 32) {
    __syncthreads();
    {
      // A: 256 chunks (32 rows x 8/row, 1 row per 128-B line); phys p holds p^(r&7)
      int rA = t >> 3, p = t & 7, l = p ^ (rA & 7);
      async_copy16(f + (size_t)(r0 + rA) * DFEAT + k0 + l * 4, (char*)As32 + t * 16);
      // B: 512 chunks (128 rows x 4); phys p holds logical p^(r&3)
      int c = t, rB = c >> 2; p = c & 3; l = p ^ (rB & 3);
      async_copy16(W1t + (size_t)rB * DFEAT + k0 + l * 8, (char*)Bs + c * 16);
      c = t + 256; rB = c >> 2; p = c & 3; l = p ^ (rB & 3);
      async_copy16(W1t + (size_t)rB * DFEAT + k0 + l * 8, (char*)Bs + c * 16);
    }
    __syncthreads();

    const int mrow = lane & 15, kq = (lane >> 4) * 8;
    short8 a, b[4];
    {
      int row = wr + mrow;
      int l0 = kq >> 2;
      int p0 = l0 ^ (row & 7), p1 = (l0 + 1) ^ (row & 7);
      float4 f0 = *(const float4*)&As32[row * 32 + p0 * 4];
      float4 f1 = *(const float4*)&As32[row * 32 + p1 * 4];
      a[0] = (short)f2bf(f0.x); a[1] = (short)f2bf(f0.y);
      a[2] = (short)f2bf(f0.z); a[3] = (short)f2bf(f0.w);
      a[4] = (short)f2bf(f1.x); a[5] = (short)f2bf(f1.y);
      a[6] = (short)f2bf(f1.z); a[7] = (short)f2bf(f1.w);
    }
#pragma unroll
    for (int nt = 0; nt < 4; nt++) {
      int row = wc + nt * 16 + mrow;
      int p = (kq >> 3) ^ (row & 3);
      b[nt] = *(const short8*)&Bs[row * 32 + p * 8];
    }
#pragma unroll
    for (int nt = 0; nt < 4; nt++)
      acc[nt] = __builtin_amdgcn_mfma_f32_16x16x32_bf16(a, b[nt], acc[nt], 0, 0, 0);
  }

  const float inv = 1.0f / sqrtf(1.0f + 1e-5f);
  const int rq = (lane >> 4) * 4, cn = lane & 15;
#pragma unroll
  for (int nt = 0; nt < 4; nt++) {
    int j = wc + nt * 16 + cn;
    float bj = b1s[j], gj = g1s[j] * inv, bej = be1s[j], wj = wls[j];
#pragma unroll
    for (int rr = 0; rr < 4; rr++) {
      int iL = wr + rq + rr;
      float pre = acc[nt][rr] + sc[iL] * wj + bj;
      h1s[iL][j] = fmaxf(gj * pre + bej, 0.f);
    }
  }
  __syncthreads();

  // layer 2: 128 -> 64. j = t&63, 8 rows/thread (broadcast LDS reads)
  {
    int j = t & 63, rg = (t >> 6) * 8;
    float a2[8];
#pragma unroll
    for (int rr = 0; rr < 8; rr++) a2[rr] = 0.f;
    for (int k = 0; k < 128; k++) {
      float w = W2[k * 64 + j];
#pragma unroll
      for (int rr = 0; rr < 8; rr++) a2[rr] = fmaf(h1s[rg + rr][k], w, a2[rr]);
    }
    float scv = g2[j] * inv, bi = b2[j], be = be2[j];
#pragma unroll
    for (int rr = 0; rr < 8; rr++)
      h2s[rg + rr][j] = fmaxf(scv * (a2[rr] + bi) + be, 0.f);
  }
  __syncthreads();

  // layer 3: 64 -> 1 + sigmoid
  if (t < 32) {
    float z = b3[0];
#pragma unroll
    for (int k = 0; k < 64; k++) z = fmaf(h2s[t][k], W3[k], z);
    ls[t] = 1.f / (1.f + __expf(-z));
  }
  __syncthreads();
  if (t == 0) {
    float s = 0.f;
#pragma unroll
    for (int iL = 0; iL < 32; iL++) s += ls[iL];
    atomicAdd(&sums[1], (double)s);
  }
}

// ---- kernel 4: combine ----
__global__ void finalize(const double* __restrict__ sums, float* __restrict__ out) {
  double simmean = sums[0] / ((double)N_IMG * (double)N_IMG);
  double aggmean = sums[1] / (double)N_IMG;
  out[0] = (float)(aggmean * simmean);
}

extern "C" void kernel_launch(void* const* d_in, const int* in_sizes, int n_in,
                              void* d_out, int out_size, void* d_ws, size_t ws_size,
                              hipStream_t stream) {
  const float* f      = (const float*)d_in[0];
  const float* scores = (const float*)d_in[1];
  const float* W1 = (const float*)d_in[2];
  const float* b1 = (const float*)d_in[3];
  const float* g1 = (const float*)d_in[4];
  const float* be1 = (const float*)d_in[5];
  const float* W2 = (const float*)d_in[6];
  const float* b2 = (const float*)d_in[7];
  const float* g2 = (const float*)d_in[8];
  const float* be2 = (const float*)d_in[9];
  const float* W3 = (const float*)d_in[10];
  const float* b3 = (const float*)d_in[11];

  // workspace layout (9.77 MB total)
  char* ws = (char*)d_ws;
  unsigned char* fb8  = (unsigned char*)ws;                  // 9,437,184 B (normalized fp8)
  float* sL           = (float*)(ws + 9437184);              // 36,864 B  (s * C1)
  float* pL           = (float*)(ws + 9474048);              // 36,864 B  (sqrt(s) * C2)
  unsigned short* W1t = (unsigned short*)(ws + 9510912);     // 262,144 B
  double* sums        = (double*)(ws + 9773056);             // 16 B

  convert_prep<<<2432, 256, 0, stream>>>(f, W1, fb8, sL, pL, W1t, sums);
  gram_sim<<<NPAIR, 256, 0, stream>>>(fb8, sL, pL, sums);
  mlp_full<<<288, 256, 0, stream>>>(f, W1t, scores, W1, b1, g1, be1,
                                    W2, b2, g2, be2, W3, b3, sums);
  finalize<<<1, 1, 0, stream>>>(sums, (float*)d_out);
}

// Round 9
// 183.938 us; speedup vs baseline: 2.4848x; 1.0781x over previous
//
#include <hip/hip_runtime.h>

#define N_IMG 9216
#define DFEAT 1024
#define NBR 72           // 128-row panels
#define NPAIR 1332       // sum over bcol<36 of min(72, 2*bcol+2)

typedef __attribute__((ext_vector_type(8))) short short8;
typedef __attribute__((ext_vector_type(4))) float floatx4;
typedef __attribute__((ext_vector_type(16))) float floatx16;
typedef __attribute__((ext_vector_type(4))) int intx4;
typedef __attribute__((ext_vector_type(8))) int intx8;

// exp2-folded constants: sim = exp2(delta - gamma * rcp(1+u))
//   delta_ij = Pi*Pj          (P = sqrt(s) * C2, C2 = sqrt(2*log2e/1024))
//   gamma_ij = s~i + s~j + delta_ij   (s~ = s * C1, C1 = log2e/1024)
// fp4 path: Gram g = sum(z_i z_j), z = 32*normalized -> u = g/1024;
// rcp(1+u) = 1024*rcp(1024+g).
#define C1F 0.0014088818759657845f
#define C2F 0.05308355472172724f

__device__ __forceinline__ void async_copy16(const void* g, void* l) {
  __builtin_amdgcn_global_load_lds((const __attribute__((address_space(1))) void*)g,
                                   (__attribute__((address_space(3))) void*)l,
                                   16, 0, 0);
}

__device__ __forceinline__ unsigned short f2bf(float x) {
  union { float f; unsigned u; } a; a.f = x;
  unsigned u = a.u;
  u += 0x7fffu + ((u >> 16) & 1u);   // round-to-nearest-even
  return (unsigned short)(u >> 16);
}

// ---- fp4 e2m1 quantizer (RNE midpoints), values {0,.5,1,1.5,2,3,4,6} ----
__device__ __forceinline__ unsigned q4(float z) {
  unsigned sg = (__float_as_uint(z) >> 28) & 8u;
  float a = fabsf(z);
  unsigned c = (a < 0.25f) ? 0u : (a < 0.75f) ? 1u : (a < 1.25f) ? 2u :
               (a < 1.75f) ? 3u : (a < 2.5f)  ? 4u : (a < 3.5f)  ? 5u :
               (a < 5.0f)  ? 6u : 7u;
  return c | sg;
}
__device__ __forceinline__ unsigned short pk4(float4 v, float sc) {
  unsigned b0 = q4(v.x * sc) | (q4(v.y * sc) << 4);
  unsigned b1 = q4(v.z * sc) | (q4(v.w * sc) << 4);
  return (unsigned short)(b0 | (b1 << 8));
}

__device__ __forceinline__ intx8 ext8(intx4 v) {
  intx8 r;
  r[0] = v[0]; r[1] = v[1]; r[2] = v[2]; r[3] = v[3];
  r[4] = 0; r[5] = 0; r[6] = 0; r[7] = 0;   // fp4 uses low 4 regs only
  return r;
}

// ---- kernel 1: fp32 -> fp4 fragment-tiled + s~/P; also W1^T bf16; init sums ----
// tiled layout: fbT[rt][kb][r32][32B], rt=row>>5 (288 tiles), kb=k>>6 (16),
// r32=row&31; one (rt,kb) slab = 1024 B = one wave's perfectly-coalesced frag.
__global__ __launch_bounds__(256) void convert_prep(const float* __restrict__ f,
                                                    const float* __restrict__ W1,
                                                    unsigned char* __restrict__ fbT,
                                                    float* __restrict__ sL,
                                                    float* __restrict__ pL,
                                                    unsigned short* __restrict__ W1t,
                                                    double* __restrict__ sums) {
  int b = blockIdx.x, t = threadIdx.x;
  if (b < 2304) {
    int lane = t & 63, wave = t >> 6;
    int row = b * 4 + wave;                      // one wave per row
    const float4* src = (const float4*)f + (size_t)row * 256;
    float4 v0 = src[lane], v1 = src[64 + lane], v2 = src[128 + lane], v3 = src[192 + lane];
    float s = v0.x * v0.x + v0.y * v0.y + v0.z * v0.z + v0.w * v0.w
            + v1.x * v1.x + v1.y * v1.y + v1.z * v1.z + v1.w * v1.w
            + v2.x * v2.x + v2.y * v2.y + v2.z * v2.z + v2.w * v2.w
            + v3.x * v3.x + v3.y * v3.y + v3.z * v3.z + v3.w * v3.w;
#pragma unroll
    for (int off = 32; off > 0; off >>= 1) s += __shfl_xor(s, off, 64);
    float zsc = rsqrtf(s) * 32.f;                // z ~ N(0,1)
    unsigned short u0 = pk4(v0, zsc), u1 = pk4(v1, zsc),
                   u2 = pk4(v2, zsc), u3 = pk4(v3, zsc);
    // lane holds elems 256j+4*lane..+3 -> kb_j = 4j + (lane>>4), byte 2*(lane&15)
    unsigned char* tb = fbT + (size_t)(row >> 5) * 16384 + (row & 31) * 32 + (lane & 15) * 2;
    int ko = (lane >> 4) * 1024;
    *(unsigned short*)(tb + ko) = u0;
    *(unsigned short*)(tb + ko + 4096) = u1;
    *(unsigned short*)(tb + ko + 8192) = u2;
    *(unsigned short*)(tb + ko + 12288) = u3;
    if (lane == 0) {
      sL[row] = s * C1F;
      pL[row] = sqrtf(s) * C2F;
    }
  } else {
    int j = b - 2304;                            // W1 column j -> W1t row j
    if (j == 0 && t < 2) sums[t] = 0.0;
    for (int k = t; k < DFEAT; k += 256)
      W1t[(size_t)j * DFEAT + k] = f2bf(W1[(size_t)k * 128 + j]);
  }
}

// ---- kernel 2: Gram via MX-fp4 MFMA, direct-from-global frags, NO LDS/barriers ----
__global__ __launch_bounds__(256, 2) void gram_sim(const unsigned char* __restrict__ fbT,
                                                   const float* __restrict__ sL,
                                                   const float* __restrict__ pL,
                                                   double* __restrict__ sums) {
  // XCD-contiguous mapping: consecutive logical L on the same XCD (blockIdx%8)
  int x = blockIdx.x & 7, ii = blockIdx.x >> 3;
  int L = (x < 4) ? x * 167 + ii : 668 + (x - 4) * 166 + ii;
  // decode L -> (bcol, brow), brow < min(72, 2*bcol+2); bcol-major (B-panel L2-hot)
  int rem = L, bcol = 0;
  for (;;) {
    int mlim = 2 * bcol + 2; if (mlim > NBR) mlim = NBR;
    if (rem < mlim) break;
    rem -= mlim; bcol++;
  }
  int brow = rem;

  __shared__ float sA[128], pA[128], sB[256], pB[256];
  __shared__ float wpart[4];

  int t = threadIdx.x, lane = t & 63, wave = t >> 6;
  if (t < 128) { sA[t] = sL[brow * 128 + t]; pA[t] = pL[brow * 128 + t]; }
  sB[t] = sL[bcol * 256 + t];
  pB[t] = pL[bcol * 256 + t];
  __syncthreads();

  const int wr = (wave & 1) * 64, wc = (wave >> 1) * 128;
  const int r32 = lane & 31, kh = lane >> 5;
  const int loff = r32 * 32 + kh * 16;

  const unsigned char* pa0 = fbT + (size_t)(brow * 4 + (wr >> 5)) * 16384 + loff;
  const unsigned char* pa1 = pa0 + 16384;
  const unsigned char* pb0 = fbT + (size_t)(bcol * 8 + (wc >> 5)) * 16384 + loff;
  const unsigned char* pb1 = pb0 + 16384;
  const unsigned char* pb2 = pb0 + 32768;
  const unsigned char* pb3 = pb0 + 49152;

  floatx16 acc[2][4];
#pragma unroll
  for (int mi = 0; mi < 2; mi++)
#pragma unroll
    for (int ni = 0; ni < 4; ni++)
#pragma unroll
      for (int e = 0; e < 16; e++) acc[mi][ni][e] = 0.f;

  intx4 aC[2], bC[4], aN[2], bN[4];
  aC[0] = *(const intx4*)pa0; aC[1] = *(const intx4*)pa1;
  bC[0] = *(const intx4*)pb0; bC[1] = *(const intx4*)pb1;
  bC[2] = *(const intx4*)pb2; bC[3] = *(const intx4*)pb3;

#pragma unroll
  for (int kb = 0; kb < 16; kb++) {
    const int o = (kb + 1) * 1024;
    if (kb < 15) {
      aN[0] = *(const intx4*)(pa0 + o); aN[1] = *(const intx4*)(pa1 + o);
      bN[0] = *(const intx4*)(pb0 + o); bN[1] = *(const intx4*)(pb1 + o);
      bN[2] = *(const intx4*)(pb2 + o); bN[3] = *(const intx4*)(pb3 + o);
    }
    intx8 A8[2], B8[4];
#pragma unroll
    for (int mi = 0; mi < 2; mi++) A8[mi] = ext8(aC[mi]);
#pragma unroll
    for (int ni = 0; ni < 4; ni++) B8[ni] = ext8(bC[ni]);
#pragma unroll
    for (int mi = 0; mi < 2; mi++)
#pragma unroll
      for (int ni = 0; ni < 4; ni++)
        acc[mi][ni] = __builtin_amdgcn_mfma_scale_f32_32x32x64_f8f6f4(
            A8[mi], B8[ni], acc[mi][ni], 4, 4,       // FMT fp4 / fp4
            0, 0x7F7F7F7F, 0, 0x7F7F7F7F);           // scales = 1.0
#pragma unroll
    for (int mi = 0; mi < 2; mi++) aC[mi] = aN[mi];
#pragma unroll
    for (int ni = 0; ni < 4; ni++) bC[ni] = bN[ni];
  }

  // epilogue: g ~= 1024*cos. C/D layout col=lane&31, row=(reg&3)+8*(reg>>2)+4*kh
  const bool interior = (brow < 2 * bcol);
  float lsum = 0.f;
#pragma unroll
  for (int ni = 0; ni < 4; ni++) {
    int j_loc = wc + ni * 32 + r32;
    float sj = sB[j_loc], pj = pB[j_loc];
    int j_g = bcol * 256 + j_loc;
#pragma unroll
    for (int mi = 0; mi < 2; mi++) {
      int rbase = wr + mi * 32 + 4 * kh;
#pragma unroll
      for (int reg = 0; reg < 16; reg++) {
        int i_loc = rbase + (reg & 3) + 8 * (reg >> 2);
        float g = acc[mi][ni][reg];
        float si = sA[i_loc], pi = pA[i_loc];
        float r = __builtin_amdgcn_rcpf(1024.f + g);
        float del = pi * pj;
        float gam = si + sj + del;
        float tt = gam * r;
        float sim = __builtin_amdgcn_exp2f(fmaf(-1024.f, tt, del));
        if (interior) {
          lsum += sim;
        } else {
          int i_g = brow * 128 + i_loc;
          lsum += (i_g < j_g) ? 2.f * sim : (i_g == j_g ? 1.f : 0.f);
        }
      }
    }
  }
  if (interior) lsum *= 2.f;
#pragma unroll
  for (int off = 32; off > 0; off >>= 1) lsum += __shfl_down(lsum, off, 64);
  if (lane == 0) wpart[wave] = lsum;
  __syncthreads();
  if (t == 0)
    atomicAdd(&sums[0], (double)(wpart[0] + wpart[1] + wpart[2] + wpart[3]));
}

// ---- kernel 3: full MLP, 32 rows/block (288 blocks): L1 bf16 MFMA, L2/L3 fp32 in LDS ----
__global__ __launch_bounds__(256) void mlp_full(const float* __restrict__ f,
                                                const unsigned short* __restrict__ W1t,
                                                const float* __restrict__ scores,
                                                const float* __restrict__ W1,
                                                const float* __restrict__ b1,
                                                const float* __restrict__ g1,
                                                const float* __restrict__ be1,
                                                const float* __restrict__ W2, const float* __restrict__ b2,
                                                const float* __restrict__ g2, const float* __restrict__ be2,
                                                const float* __restrict__ W3, const float* __restrict__ b3,
                                                double* __restrict__ sums) {
  int r0 = blockIdx.x * 32;

  __shared__ __align__(16) float As32[32 * 32];         // 4 KB, XOR-swizzled chunks
  __shared__ __align__(16) unsigned short Bs[128 * 32]; // 8 KB, XOR-swizzled chunks
  __shared__ float h1s[32][128];                        // 16 KB
  __shared__ float h2s[32][65];                         // 8.3 KB
  __shared__ float sc[32], b1s[128], g1s[128], be1s[128], wls[128], ls[32];

  int t = threadIdx.x, lane = t & 63, wave = t >> 6;
  if (t < 32) sc[t] = scores[r0 + t];
  if (t < 128) {
    b1s[t] = b1[t]; g1s[t] = g1[t]; be1s[t] = be1[t];
    wls[t] = W1[(size_t)DFEAT * 128 + t];
  }

  floatx4 acc[4];
#pragma unroll
  for (int b = 0; b < 4; b++) acc[b] = (floatx4){0.f, 0.f, 0.f, 0.f};

  const int wr = (wave & 1) * 16, wc = (wave >> 1) * 64;

  for (int k0 = 0; k0 < DFEAT; k0 += 32) {
    __syncthreads();
    {
      // A: 256 chunks (32 rows x 8/row, 1 row per 128-B line); phys p holds p^(r&7)
      int rA = t >> 3, p = t & 7, l = p ^ (rA & 7);
      async_copy16(f + (size_t)(r0 + rA) * DFEAT + k0 + l * 4, (char*)As32 + t * 16);
      // B: 512 chunks (128 rows x 4); phys p holds logical p^(r&3)
      int c = t, rB = c >> 2; p = c & 3; l = p ^ (rB & 3);
      async_copy16(W1t + (size_t)rB * DFEAT + k0 + l * 8, (char*)Bs + c * 16);
      c = t + 256; rB = c >> 2; p = c & 3; l = p ^ (rB & 3);
      async_copy16(W1t + (size_t)rB * DFEAT + k0 + l * 8, (char*)Bs + c * 16);
    }
    __syncthreads();

    const int mrow = lane & 15, kq = (lane >> 4) * 8;
    short8 a, b[4];
    {
      int row = wr + mrow;
      int l0 = kq >> 2;
      int p0 = l0 ^ (row & 7), p1 = (l0 + 1) ^ (row & 7);
      float4 f0 = *(const float4*)&As32[row * 32 + p0 * 4];
      float4 f1 = *(const float4*)&As32[row * 32 + p1 * 4];
      a[0] = (short)f2bf(f0.x); a[1] = (short)f2bf(f0.y);
      a[2] = (short)f2bf(f0.z); a[3] = (short)f2bf(f0.w);
      a[4] = (short)f2bf(f1.x); a[5] = (short)f2bf(f1.y);
      a[6] = (short)f2bf(f1.z); a[7] = (short)f2bf(f1.w);
    }
#pragma unroll
    for (int nt = 0; nt < 4; nt++) {
      int row = wc + nt * 16 + mrow;
      int p = (kq >> 3) ^ (row & 3);
      b[nt] = *(const short8*)&Bs[row * 32 + p * 8];
    }
#pragma unroll
    for (int nt = 0; nt < 4; nt++)
      acc[nt] = __builtin_amdgcn_mfma_f32_16x16x32_bf16(a, b[nt], acc[nt], 0, 0, 0);
  }

  const float inv = 1.0f / sqrtf(1.0f + 1e-5f);
  const int rq = (lane >> 4) * 4, cn = lane & 15;
#pragma unroll
  for (int nt = 0; nt < 4; nt++) {
    int j = wc + nt * 16 + cn;
    float bj = b1s[j], gj = g1s[j] * inv, bej = be1s[j], wj = wls[j];
#pragma unroll
    for (int rr = 0; rr < 4; rr++) {
      int iL = wr + rq + rr;
      float pre = acc[nt][rr] + sc[iL] * wj + bj;
      h1s[iL][j] = fmaxf(gj * pre + bej, 0.f);
    }
  }
  __syncthreads();

  // layer 2: 128 -> 64. j = t&63, 8 rows/thread (broadcast LDS reads)
  {
    int j = t & 63, rg = (t >> 6) * 8;
    float a2[8];
#pragma unroll
    for (int rr = 0; rr < 8; rr++) a2[rr] = 0.f;
    for (int k = 0; k < 128; k++) {
      float w = W2[k * 64 + j];
#pragma unroll
      for (int rr = 0; rr < 8; rr++) a2[rr] = fmaf(h1s[rg + rr][k], w, a2[rr]);
    }
    float scv = g2[j] * inv, bi = b2[j], be = be2[j];
#pragma unroll
    for (int rr = 0; rr < 8; rr++)
      h2s[rg + rr][j] = fmaxf(scv * (a2[rr] + bi) + be, 0.f);
  }
  __syncthreads();

  // layer 3: 64 -> 1 + sigmoid
  if (t < 32) {
    float z = b3[0];
#pragma unroll
    for (int k = 0; k < 64; k++) z = fmaf(h2s[t][k], W3[k], z);
    ls[t] = 1.f / (1.f + __expf(-z));
  }
  __syncthreads();
  if (t == 0) {
    float s = 0.f;
#pragma unroll
    for (int iL = 0; iL < 32; iL++) s += ls[iL];
    atomicAdd(&sums[1], (double)s);
  }
}

// ---- kernel 4: combine ----
__global__ void finalize(const double* __restrict__ sums, float* __restrict__ out) {
  double simmean = sums[0] / ((double)N_IMG * (double)N_IMG);
  double aggmean = sums[1] / (double)N_IMG;
  out[0] = (float)(aggmean * simmean);
}

extern "C" void kernel_launch(void* const* d_in, const int* in_sizes, int n_in,
                              void* d_out, int out_size, void* d_ws, size_t ws_size,
                              hipStream_t stream) {
  const float* f      = (const float*)d_in[0];
  const float* scores = (const float*)d_in[1];
  const float* W1 = (const float*)d_in[2];
  const float* b1 = (const float*)d_in[3];
  const float* g1 = (const float*)d_in[4];
  const float* be1 = (const float*)d_in[5];
  const float* W2 = (const float*)d_in[6];
  const float* b2 = (const float*)d_in[7];
  const float* g2 = (const float*)d_in[8];
  const float* be2 = (const float*)d_in[9];
  const float* W3 = (const float*)d_in[10];
  const float* b3 = (const float*)d_in[11];

  // workspace layout (~5.05 MB total)
  char* ws = (char*)d_ws;
  unsigned char* fbT  = (unsigned char*)ws;                  // 4,718,592 B (fp4 tiled)
  float* sL           = (float*)(ws + 4718592);              // 36,864 B  (s * C1)
  float* pL           = (float*)(ws + 4755456);              // 36,864 B  (sqrt(s) * C2)
  unsigned short* W1t = (unsigned short*)(ws + 4792320);     // 262,144 B
  double* sums        = (double*)(ws + 5054464);             // 16 B

  convert_prep<<<2432, 256, 0, stream>>>(f, W1, fbT, sL, pL, W1t, sums);
  gram_sim<<<NPAIR, 256, 0, stream>>>(fbT, sL, pL, sums);
  mlp_full<<<288, 256, 0, stream>>>(f, W1t, scores, W1, b1, g1, be1,
                                    W2, b2, g2, be2, W3, b3, sums);
  finalize<<<1, 1, 0, stream>>>(sums, (float*)d_out);
}

// Round 10
// 181.346 us; speedup vs baseline: 2.5203x; 1.0143x over previous
//
#include <hip/hip_runtime.h>

#define N_IMG 9216
#define DFEAT 1024
#define NBR 72           // 128-row panels
#define NPAIR 1332       // sum over bcol<36 of min(72, 2*bcol+2)

typedef __attribute__((ext_vector_type(8))) short short8;
typedef __attribute__((ext_vector_type(4))) float floatx4;
typedef __attribute__((ext_vector_type(16))) float floatx16;
typedef __attribute__((ext_vector_type(4))) int intx4;
typedef __attribute__((ext_vector_type(8))) int intx8;

// exp2-folded constants: sim = exp2(delta - gamma * rcp(1+u))
//   delta_ij = Pi*Pj          (P = sqrt(s) * C2, C2 = sqrt(2*log2e/1024))
//   gamma_ij = s~i + s~j + delta_ij   (s~ = s * C1, C1 = log2e/1024)
// fp4 path: Gram g = sum(z_i z_j), z = 32*normalized -> u = g/1024;
// rcp(1+u) = 1024*rcp(1024+g).
#define C1F 0.0014088818759657845f
#define C2F 0.05308355472172724f

__device__ __forceinline__ void async_copy16(const void* g, void* l) {
  __builtin_amdgcn_global_load_lds((const __attribute__((address_space(1))) void*)g,
                                   (__attribute__((address_space(3))) void*)l,
                                   16, 0, 0);
}

__device__ __forceinline__ unsigned short f2bf(float x) {
  union { float f; unsigned u; } a; a.f = x;
  unsigned u = a.u;
  u += 0x7fffu + ((u >> 16) & 1u);   // round-to-nearest-even
  return (unsigned short)(u >> 16);
}

// ---- fp4 e2m1 quantizer (RNE midpoints), values {0,.5,1,1.5,2,3,4,6} ----
__device__ __forceinline__ unsigned q4(float z) {
  unsigned sg = (__float_as_uint(z) >> 28) & 8u;
  float a = fabsf(z);
  unsigned c = (a < 0.25f) ? 0u : (a < 0.75f) ? 1u : (a < 1.25f) ? 2u :
               (a < 1.75f) ? 3u : (a < 2.5f)  ? 4u : (a < 3.5f)  ? 5u :
               (a < 5.0f)  ? 6u : 7u;
  return c | sg;
}
__device__ __forceinline__ unsigned short pk4(float4 v, float sc) {
  unsigned b0 = q4(v.x * sc) | (q4(v.y * sc) << 4);
  unsigned b1 = q4(v.z * sc) | (q4(v.w * sc) << 4);
  return (unsigned short)(b0 | (b1 << 8));
}

__device__ __forceinline__ intx8 ext8(intx4 v) {
  intx8 r;
  r[0] = v[0]; r[1] = v[1]; r[2] = v[2]; r[3] = v[3];
  r[4] = 0; r[5] = 0; r[6] = 0; r[7] = 0;   // fp4 uses low 4 regs only
  return r;
}

// ---- kernel 1: fp32 -> fp4 fragment-tiled + s~/P; also W1^T bf16; init sums ----
// tiled layout: fbT[rt][kb][r32][32B], rt=row>>5 (288 tiles), kb=k>>6 (16),
// r32=row&31; one (rt,kb) slab = 1024 B = one wave's perfectly-coalesced frag.
__global__ __launch_bounds__(256) void convert_prep(const float* __restrict__ f,
                                                    const float* __restrict__ W1,
                                                    unsigned char* __restrict__ fbT,
                                                    float* __restrict__ sL,
                                                    float* __restrict__ pL,
                                                    unsigned short* __restrict__ W1t,
                                                    double* __restrict__ sums) {
  int b = blockIdx.x, t = threadIdx.x;
  if (b < 2304) {
    int lane = t & 63, wave = t >> 6;
    int row = b * 4 + wave;                      // one wave per row
    const float4* src = (const float4*)f + (size_t)row * 256;
    float4 v0 = src[lane], v1 = src[64 + lane], v2 = src[128 + lane], v3 = src[192 + lane];
    float s = v0.x * v0.x + v0.y * v0.y + v0.z * v0.z + v0.w * v0.w
            + v1.x * v1.x + v1.y * v1.y + v1.z * v1.z + v1.w * v1.w
            + v2.x * v2.x + v2.y * v2.y + v2.z * v2.z + v2.w * v2.w
            + v3.x * v3.x + v3.y * v3.y + v3.z * v3.z + v3.w * v3.w;
#pragma unroll
    for (int off = 32; off > 0; off >>= 1) s += __shfl_xor(s, off, 64);
    float zsc = rsqrtf(s) * 32.f;                // z ~ N(0,1)
    unsigned short u0 = pk4(v0, zsc), u1 = pk4(v1, zsc),
                   u2 = pk4(v2, zsc), u3 = pk4(v3, zsc);
    // lane holds elems 256j+4*lane..+3 -> kb_j = 4j + (lane>>4), byte 2*(lane&15)
    unsigned char* tb = fbT + (size_t)(row >> 5) * 16384 + (row & 31) * 32 + (lane & 15) * 2;
    int ko = (lane >> 4) * 1024;
    *(unsigned short*)(tb + ko) = u0;
    *(unsigned short*)(tb + ko + 4096) = u1;
    *(unsigned short*)(tb + ko + 8192) = u2;
    *(unsigned short*)(tb + ko + 12288) = u3;
    if (lane == 0) {
      sL[row] = s * C1F;
      pL[row] = sqrtf(s) * C2F;
    }
  } else {
    int j = b - 2304;                            // W1 column j -> W1t row j
    if (j == 0 && t < 2) sums[t] = 0.0;
    for (int k = t; k < DFEAT; k += 256)
      W1t[(size_t)j * DFEAT + k] = f2bf(W1[(size_t)k * 128 + j]);
  }
}

// ---- kernel 2: Gram via MX-fp4 MFMA, direct-from-global frags, depth-2 pipeline ----
__global__ __launch_bounds__(256, 2) void gram_sim(const unsigned char* __restrict__ fbT,
                                                   const float* __restrict__ sL,
                                                   const float* __restrict__ pL,
                                                   double* __restrict__ sums) {
  // XCD-contiguous mapping: consecutive logical L on the same XCD (blockIdx%8)
  int x = blockIdx.x & 7, ii = blockIdx.x >> 3;
  int L = (x < 4) ? x * 167 + ii : 668 + (x - 4) * 166 + ii;
  // decode L -> (bcol, brow), brow < min(72, 2*bcol+2); bcol-major (B-panel L2-hot)
  int rem = L, bcol = 0;
  for (;;) {
    int mlim = 2 * bcol + 2; if (mlim > NBR) mlim = NBR;
    if (rem < mlim) break;
    rem -= mlim; bcol++;
  }
  int brow = rem;

  __shared__ float sA[128], pA[128], sB[256], pB[256];
  __shared__ float wpart[4];

  int t = threadIdx.x, lane = t & 63, wave = t >> 6;
  if (t < 128) { sA[t] = sL[brow * 128 + t]; pA[t] = pL[brow * 128 + t]; }
  sB[t] = sL[bcol * 256 + t];
  pB[t] = pL[bcol * 256 + t];
  __syncthreads();

  const int wr = (wave & 1) * 64, wc = (wave >> 1) * 128;
  const int r32 = lane & 31, kh = lane >> 5;
  const int loff = r32 * 32 + kh * 16;

  const unsigned char* pa0 = fbT + (size_t)(brow * 4 + (wr >> 5)) * 16384 + loff;
  const unsigned char* pa1 = pa0 + 16384;
  const unsigned char* pb0 = fbT + (size_t)(bcol * 8 + (wc >> 5)) * 16384 + loff;
  const unsigned char* pb1 = pb0 + 16384;
  const unsigned char* pb2 = pb0 + 32768;
  const unsigned char* pb3 = pb0 + 49152;

  floatx16 acc[2][4];
#pragma unroll
  for (int mi = 0; mi < 2; mi++)
#pragma unroll
    for (int ni = 0; ni < 4; ni++)
#pragma unroll
      for (int e = 0; e < 16; e++) acc[mi][ni][e] = 0.f;

  // depth-2 software pipeline: 3 register buffer sets, loads issue 2 iters ahead
  intx4 bA[3][2], bB[3][4];
#define LDSET(s, kb)                                                        \
  {                                                                         \
    const int o = (kb) * 1024;                                              \
    bA[s][0] = *(const intx4*)(pa0 + o); bA[s][1] = *(const intx4*)(pa1 + o); \
    bB[s][0] = *(const intx4*)(pb0 + o); bB[s][1] = *(const intx4*)(pb1 + o); \
    bB[s][2] = *(const intx4*)(pb2 + o); bB[s][3] = *(const intx4*)(pb3 + o); \
  }
  LDSET(0, 0)
  LDSET(1, 1)
#pragma unroll
  for (int kb = 0; kb < 16; kb++) {
    const int cur = kb % 3, nxt = (kb + 2) % 3;
    if (kb < 14) LDSET(nxt, kb + 2)
    intx8 A8[2], B8[4];
#pragma unroll
    for (int mi = 0; mi < 2; mi++) A8[mi] = ext8(bA[cur][mi]);
#pragma unroll
    for (int ni = 0; ni < 4; ni++) B8[ni] = ext8(bB[cur][ni]);
#pragma unroll
    for (int mi = 0; mi < 2; mi++)
#pragma unroll
      for (int ni = 0; ni < 4; ni++)
        acc[mi][ni] = __builtin_amdgcn_mfma_scale_f32_32x32x64_f8f6f4(
            A8[mi], B8[ni], acc[mi][ni], 4, 4,       // FMT fp4 / fp4
            0, 0x7F7F7F7F, 0, 0x7F7F7F7F);           // scales = 1.0
  }
#undef LDSET

  // epilogue: g ~= 1024*cos. C/D layout col=lane&31, row=(reg&3)+8*(reg>>2)+4*kh
  const bool interior = (brow < 2 * bcol);
  float lsum = 0.f;
#pragma unroll
  for (int ni = 0; ni < 4; ni++) {
    int j_loc = wc + ni * 32 + r32;
    float sj = sB[j_loc], pj = pB[j_loc];
    int j_g = bcol * 256 + j_loc;
#pragma unroll
    for (int mi = 0; mi < 2; mi++) {
      int rbase = wr + mi * 32 + 4 * kh;
#pragma unroll
      for (int reg = 0; reg < 16; reg++) {
        int i_loc = rbase + (reg & 3) + 8 * (reg >> 2);
        float g = acc[mi][ni][reg];
        float si = sA[i_loc], pi = pA[i_loc];
        float r = __builtin_amdgcn_rcpf(1024.f + g);
        float del = pi * pj;
        float gam = si + sj + del;
        float tt = gam * r;
        float sim = __builtin_amdgcn_exp2f(fmaf(-1024.f, tt, del));
        if (interior) {
          lsum += sim;
        } else {
          int i_g = brow * 128 + i_loc;
          lsum += (i_g < j_g) ? 2.f * sim : (i_g == j_g ? 1.f : 0.f);
        }
      }
    }
  }
  if (interior) lsum *= 2.f;
#pragma unroll
  for (int off = 32; off > 0; off >>= 1) lsum += __shfl_down(lsum, off, 64);
  if (lane == 0) wpart[wave] = lsum;
  __syncthreads();
  if (t == 0)
    atomicAdd(&sums[0], (double)(wpart[0] + wpart[1] + wpart[2] + wpart[3]));
}

// ---- kernel 3: full MLP, 32 rows/block (288 blocks), BK=64 (32 barriers) ----
__global__ __launch_bounds__(256) void mlp_full(const float* __restrict__ f,
                                                const unsigned short* __restrict__ W1t,
                                                const float* __restrict__ scores,
                                                const float* __restrict__ W1,
                                                const float* __restrict__ b1,
                                                const float* __restrict__ g1,
                                                const float* __restrict__ be1,
                                                const float* __restrict__ W2, const float* __restrict__ b2,
                                                const float* __restrict__ g2, const float* __restrict__ be2,
                                                const float* __restrict__ W3, const float* __restrict__ b3,
                                                double* __restrict__ sums) {
  int r0 = blockIdx.x * 32;

  __shared__ __align__(16) float As32[32 * 64];         // 8 KB, 16-slot XOR swizzle
  __shared__ __align__(16) unsigned short Bs[128 * 64]; // 16 KB, 8-slot XOR swizzle
  __shared__ float h1s[32][128];                        // 16 KB
  __shared__ float h2s[32][65];                         // 8.3 KB
  __shared__ float sc[32], b1s[128], g1s[128], be1s[128], wls[128], ls[32];

  int t = threadIdx.x, lane = t & 63, wave = t >> 6;
  if (t < 32) sc[t] = scores[r0 + t];
  if (t < 128) {
    b1s[t] = b1[t]; g1s[t] = g1[t]; be1s[t] = be1[t];
    wls[t] = W1[(size_t)DFEAT * 128 + t];
  }

  floatx4 acc[4];
#pragma unroll
  for (int b = 0; b < 4; b++) acc[b] = (floatx4){0.f, 0.f, 0.f, 0.f};

  const int wr = (wave & 1) * 16, wc = (wave >> 1) * 64;

  for (int k0 = 0; k0 < DFEAT; k0 += 64) {
    __syncthreads();
    {
      // A: 512 chunks (32 rows x 16/row); phys p of row r holds logical p^(r&15)
      int c = t, rA = c >> 4, p = c & 15, l = p ^ (rA & 15);
      async_copy16(f + (size_t)(r0 + rA) * DFEAT + k0 + l * 4, (char*)As32 + c * 16);
      c = t + 256; rA = c >> 4; p = c & 15; l = p ^ (rA & 15);
      async_copy16(f + (size_t)(r0 + rA) * DFEAT + k0 + l * 4, (char*)As32 + c * 16);
      // B: 1024 chunks (128 rows x 8/row); phys p holds logical p^(r&7)
#pragma unroll
      for (int q = 0; q < 4; q++) {
        int cc = t + q * 256, rB = cc >> 3, pp = cc & 7, ll = pp ^ (rB & 7);
        async_copy16(W1t + (size_t)rB * DFEAT + k0 + ll * 8, (char*)Bs + cc * 16);
      }
    }
    __syncthreads();

    const int mrow = lane & 15;
#pragma unroll
    for (int ks = 0; ks < 2; ks++) {
      const int kq = ks * 32 + (lane >> 4) * 8;
      short8 a, b[4];
      {
        int row = wr + mrow;
        int l0 = kq >> 2;
        int p0 = l0 ^ (row & 15), p1 = (l0 + 1) ^ (row & 15);
        float4 f0 = *(const float4*)&As32[row * 64 + p0 * 4];
        float4 f1 = *(const float4*)&As32[row * 64 + p1 * 4];
        a[0] = (short)f2bf(f0.x); a[1] = (short)f2bf(f0.y);
        a[2] = (short)f2bf(f0.z); a[3] = (short)f2bf(f0.w);
        a[4] = (short)f2bf(f1.x); a[5] = (short)f2bf(f1.y);
        a[6] = (short)f2bf(f1.z); a[7] = (short)f2bf(f1.w);
      }
#pragma unroll
      for (int nt = 0; nt < 4; nt++) {
        int row = wc + nt * 16 + mrow;
        int p = (kq >> 3) ^ (row & 7);
        b[nt] = *(const short8*)&Bs[row * 64 + p * 8];
      }
#pragma unroll
      for (int nt = 0; nt < 4; nt++)
        acc[nt] = __builtin_amdgcn_mfma_f32_16x16x32_bf16(a, b[nt], acc[nt], 0, 0, 0);
    }
  }

  const float inv = 1.0f / sqrtf(1.0f + 1e-5f);
  const int rq = (lane >> 4) * 4, cn = lane & 15;
#pragma unroll
  for (int nt = 0; nt < 4; nt++) {
    int j = wc + nt * 16 + cn;
    float bj = b1s[j], gj = g1s[j] * inv, bej = be1s[j], wj = wls[j];
#pragma unroll
    for (int rr = 0; rr < 4; rr++) {
      int iL = wr + rq + rr;
      float pre = acc[nt][rr] + sc[iL] * wj + bj;
      h1s[iL][j] = fmaxf(gj * pre + bej, 0.f);
    }
  }
  __syncthreads();

  // layer 2: 128 -> 64. j = t&63, 8 rows/thread (broadcast LDS reads)
  {
    int j = t & 63, rg = (t >> 6) * 8;
    float a2[8];
#pragma unroll
    for (int rr = 0; rr < 8; rr++) a2[rr] = 0.f;
    for (int k = 0; k < 128; k++) {
      float w = W2[k * 64 + j];
#pragma unroll
      for (int rr = 0; rr < 8; rr++) a2[rr] = fmaf(h1s[rg + rr][k], w, a2[rr]);
    }
    float scv = g2[j] * inv, bi = b2[j], be = be2[j];
#pragma unroll
    for (int rr = 0; rr < 8; rr++)
      h2s[rg + rr][j] = fmaxf(scv * (a2[rr] + bi) + be, 0.f);
  }
  __syncthreads();

  // layer 3: 64 -> 1 + sigmoid
  if (t < 32) {
    float z = b3[0];
#pragma unroll
    for (int k = 0; k < 64; k++) z = fmaf(h2s[t][k], W3[k], z);
    ls[t] = 1.f / (1.f + __expf(-z));
  }
  __syncthreads();
  if (t == 0) {
    float s = 0.f;
#pragma unroll
    for (int iL = 0; iL < 32; iL++) s += ls[iL];
    atomicAdd(&sums[1], (double)s);
  }
}

// ---- kernel 4: combine ----
__global__ void finalize(const double* __restrict__ sums, float* __restrict__ out) {
  double simmean = sums[0] / ((double)N_IMG * (double)N_IMG);
  double aggmean = sums[1] / (double)N_IMG;
  out[0] = (float)(aggmean * simmean);
}

extern "C" void kernel_launch(void* const* d_in, const int* in_sizes, int n_in,
                              void* d_out, int out_size, void* d_ws, size_t ws_size,
                              hipStream_t stream) {
  const float* f      = (const float*)d_in[0];
  const float* scores = (const float*)d_in[1];
  const float* W1 = (const float*)d_in[2];
  const float* b1 = (const float*)d_in[3];
  const float* g1 = (const float*)d_in[4];
  const float* be1 = (const float*)d_in[5];
  const float* W2 = (const float*)d_in[6];
  const float* b2 = (const float*)d_in[7];
  const float* g2 = (const float*)d_in[8];
  const float* be2 = (const float*)d_in[9];
  const float* W3 = (const float*)d_in[10];
  const float* b3 = (const float*)d_in[11];

  // workspace layout (~5.05 MB total)
  char* ws = (char*)d_ws;
  unsigned char* fbT  = (unsigned char*)ws;                  // 4,718,592 B (fp4 tiled)
  float* sL           = (float*)(ws + 4718592);              // 36,864 B  (s * C1)
  float* pL           = (float*)(ws + 4755456);              // 36,864 B  (sqrt(s) * C2)
  unsigned short* W1t = (unsigned short*)(ws + 4792320);     // 262,144 B
  double* sums        = (double*)(ws + 5054464);             // 16 B

  convert_prep<<<2432, 256, 0, stream>>>(f, W1, fbT, sL, pL, W1t, sums);
  gram_sim<<<NPAIR, 256, 0, stream>>>(fbT, sL, pL, sums);
  mlp_full<<<288, 256, 0, stream>>>(f, W1t, scores, W1, b1, g1, be1,
                                    W2, b2, g2, be2, W3, b3, sums);
  finalize<<<1, 1, 0, stream>>>(sums, (float*)d_out);
}